// Round 4
// baseline (291.391 us; speedup 1.0000x reference)
//
#include <hip/hip_runtime.h>
#include <math.h>

#define BB 16
#define KK 128
#define NC 80
#define OH 128
#define OW 128
#define NPIX (OH * OW)
#define NBLK (BB * KK)
#define ALPHA_C 0.54f

// ---------------- ws layout (bytes) ----------------
//   0:  int    counter
//   4:  int    np
//   8:  double neg
//   16: double pos
//   24: double rw
//   32: double wl
// (zeroed by a 64 B hipMemsetAsync each call; everything else lives in LDS)

struct Accum {
  int counter;
  int np;
  double neg;
  double pos;
  double rw;
  double wl;
};

__device__ __forceinline__ int iabs_(int x) { return x < 0 ? -x : x; }

// baseline negative-loss term at heatmap==0; MUST be identical in dense and corr paths
__device__ __forceinline__ float neg_base(float v) {
  float pred = 1.f / (1.f + __expf(-v));
  pred = fminf(fmaxf(pred, 1e-4f), 0.9999f);
  return __logf(1.f - pred) * pred * pred;
}

// One kernel does everything. Block (b,k): b = image, k = sorted box index.
// Phase 0: grid-stride dense heatmap==0 baseline over all of hm (pure HBM stream).
// Phase 1: redundant per-block prep (mask detect, bitonic sort, box params) in LDS.
// Phase 2: sparse heatmap correction for box k (16x16 thread tile over its window).
// Phase 3: wh/IoU loss for row k of image b (winner = descending LDS scan).
// Phase 4: block reduce -> global f64 atomics; last block computes final loss.
__global__ __launch_bounds__(256) void k_all(
    const float* hm, const float* __restrict__ wh,
    const float* __restrict__ tgt, const void* __restrict__ maskp,
    Accum* __restrict__ acc, float* __restrict__ out)
{
  int tid = threadIdx.x;
  int blk = blockIdx.x;
  int b = blk >> 7;          // image
  int k = blk & (KK - 1);    // sorted box index handled by this block

  __shared__ float skey[KK];
  __shared__ int   sidx[KK];
  __shared__ float sal[KK];
  __shared__ int   spk[KK], scl[KK], sl[KK];
  __shared__ float si2x[KK], si2y[KK], scf[KK];
  __shared__ float sx1[KK], sy1[KK], sx2[KK], sy2[KK];
  __shared__ int   anyBig, anyF1, snS;

  // ---- phase 0: dense heatmap==0 baseline (no LDS dependency — HBM from cycle 0) ----
  float negS = 0.f;
  {
    const float4* hm4 = (const float4*)hm;
    const int n4 = BB * NC * NPIX / 4;
    int stride = gridDim.x * blockDim.x;
    for (int i = blk * 256 + tid; i < n4; i += stride) {
      float4 v = hm4[i];
      negS += neg_base(v.x) + neg_base(v.y) + neg_base(v.z) + neg_base(v.w);
    }
  }

  // ---- phase 1: per-block prep (redundant across the 128 blocks of each image) ----
  if (tid == 0) { anyBig = 0; anyF1 = 0; }
  __syncthreads();
  // mask dtype auto-detect: scan first 512 words (2048 bytes, safe for all layouts)
  const unsigned int* mu = (const unsigned int*)maskp;
  for (int i = tid; i < 512; i += 256) {
    unsigned int u = mu[i];
    if (u == 0x3f800000u) anyF1 = 1;
    else if (u > 1u) anyBig = 1;
  }
  __syncthreads();
  int mode = anyF1 ? 2 : (anyBig ? 1 : 0);  // 0=int32, 1=uint8, 2=float32

  const float* tb = tgt + b * KK * 5;
  if (tid < KK) {
    int gi = b * KK + tid;
    bool m;
    if (mode == 2)      m = ((const float*)maskp)[gi] != 0.f;
    else if (mode == 1) m = ((const unsigned char*)maskp)[gi] != 0;
    else                m = ((const int*)maskp)[gi] != 0;
    float x1 = tb[tid * 5 + 1], y1 = tb[tid * 5 + 2];
    float x2 = tb[tid * 5 + 3], y2 = tb[tid * 5 + 4];
    float alog = logf((x2 - x1) * (y2 - y1));
    // ascending sort of (valid ? -area_log : +inf) == argsort(-sort_key)
    skey[tid] = m ? -alog : INFINITY;
    sidx[tid] = tid;
  }
  __syncthreads();

  for (int size = 2; size <= KK; size <<= 1) {
    for (int stride = size >> 1; stride > 0; stride >>= 1) {
      if (tid < KK) {
        int i = tid, j = i ^ stride;
        if (j > i) {
          bool up = ((i & size) == 0);
          float ki = skey[i], kj = skey[j];
          if (up ? (ki > kj) : (ki < kj)) {
            skey[i] = kj; skey[j] = ki;
            int t = sidx[i]; sidx[i] = sidx[j]; sidx[j] = t;
          }
        }
      }
      __syncthreads();
    }
  }

  if (tid < KK) {
    int o = sidx[tid];
    int go = b * KK + o;
    bool vo;
    if (mode == 2)      vo = ((const float*)maskp)[go] != 0.f;
    else if (mode == 1) vo = ((const unsigned char*)maskp)[go] != 0;
    else                vo = ((const int*)maskp)[go] != 0;
    float bx1 = tb[o * 5 + 1], by1 = tb[o * 5 + 2];
    float bx2 = tb[o * 5 + 3], by2 = tb[o * 5 + 4];
    float al = vo ? logf((bx2 - bx1) * (by2 - by1)) : 0.f;
    sal[tid] = al;
    scl[tid] = (int)tb[o * 5 + 0];
    sx1[tid] = bx1; sy1[tid] = by1; sx2[tid] = bx2; sy2[tid] = by2;
    // stash validity for the next step via spk sentinel later; recompute below
    sidx[tid] = vo ? 1 : 0;
  }
  __syncthreads();

  if (tid < KK) {
    float al0 = sal[0];
    float factor = 2.f - sal[tid] / (al0 + 1e-7f);
    float bx1 = sx1[tid], by1 = sy1[tid], bx2 = sx2[tid], by2 = sy2[tid];
    float fx1 = fminf(fmaxf(bx1 * 0.25f, 0.f), (float)(OW - 1));
    float fy1 = fminf(fmaxf(by1 * 0.25f, 0.f), (float)(OH - 1));
    float fx2 = fminf(fmaxf(bx2 * 0.25f, 0.f), (float)(OW - 1));
    float fy2 = fminf(fmaxf(by2 * 0.25f, 0.f), (float)(OH - 1));
    float fh = fy2 - fy1, fw = fx2 - fx1;
    int cx = (int)((bx1 + bx2) * 0.125f);
    int cy = (int)((by1 + by2) * 0.125f);
    int hr = (int)(fh * 0.5f * ALPHA_C);
    int wr = (int)(fw * 0.5f * ALPHA_C);
    float sy = (float)(2 * hr + 1) / 6.f;
    float sxx = (float)(2 * wr + 1) / 6.f;
    float i2y = 1.f / (2.f * sy * sy);
    float i2x = 1.f / (2.f * sxx * sxx);
    bool inb = (cx >= 0 && cx < OW && cy >= 0 && cy < OH);
    bool cov = (sidx[tid] != 0) && inb;

    float sgy = 0.f, sgx = 0.f;
    if (cov) {
      int y0 = max(0, cy - hr), y1i = min(OH - 1, cy + hr);
      for (int y = y0; y <= y1i; ++y) { float d = (float)(y - cy); sgy += __expf(-d * d * i2y); }
      int x0 = max(0, cx - wr), x1i = min(OW - 1, cx + wr);
      for (int x = x0; x <= x1i; ++x) { float d = (float)(x - cx); sgx += __expf(-d * d * i2x); }
    }
    float div = cov ? sgy * sgx : 0.f;
    scf[tid] = factor / (div + 1e-7f);
    si2x[tid] = i2x; si2y[tid] = i2y;
    spk[tid] = cov ? ((cx & 255) | ((cy & 255) << 8) | ((wr & 255) << 16) | ((hr & 255) << 24))
                   : 0x000000FF;  // cx=255: |px-255| <= wr impossible for px in [0,128)
  }
  __syncthreads();

  int pk = spk[k];
  int cx = pk & 255, cy = (pk >> 8) & 255, wr = (pk >> 16) & 255, hr = (pk >> 24) & 255;
  int c = scl[k];

  // ---- wave 0: ballot-compact same-class box indices (ascending) ----
  if (cx != 255 && tid < 64) {
    unsigned long long below = (1ull << tid) - 1ull;
    bool p0 = (scl[tid] == c);
    unsigned long long m0 = __ballot(p0);
    int n0 = __popcll(m0);
    if (p0) sl[__popcll(m0 & below)] = tid;
    bool p1 = (scl[tid + 64] == c);
    unsigned long long m1 = __ballot(p1);
    if (p1) sl[n0 + __popcll(m1 & below)] = tid + 64;
    if (tid == 0) snS = n0 + __popcll(m1);
  }
  __syncthreads();

  // ---- phase 2: sparse heatmap correction for box k (16x16 thread tile) ----
  float posS = 0.f;
  int np = 0;
  if (cx != 255) {
    int nS = snS;
    int W = 2 * wr + 1, H = 2 * hr + 1;
    int tr = tid >> 4, tc = tid & 15;
    for (int r0 = 0; r0 < H; r0 += 16) {
      int row = r0 + tr;
      int py = cy - hr + row;
      if (row >= H || py < 0 || py >= OH) continue;
      for (int c0 = 0; c0 < W; c0 += 16) {
        int col = c0 + tc;
        int px = cx - wr + col;
        if (col >= W || px < 0 || px >= OW) continue;
        float h = 0.f;
        bool center = false, resp = true;
        for (int u = 0; u < nS; ++u) {
          int j = sl[u];
          int pj = spk[j];
          int dx = px - (pj & 255), dy = py - ((pj >> 8) & 255);
          if (iabs_(dx) <= ((pj >> 16) & 255) && iabs_(dy) <= ((pj >> 24) & 255)) {
            if (j < k) { resp = false; break; }  // smaller sorted index owns this cell
            float g = __expf(-(float)(dy * dy) * si2y[j] - (float)(dx * dx) * si2x[j]);
            h = fmaxf(h, g);
            center |= (dx == 0 && dy == 0);
          }
        }
        if (!resp) continue;
        float v = hm[((b * NC + c) * OH + py) * OW + px];
        float pred = 1.f / (1.f + __expf(-v));
        pred = fminf(fmaxf(pred, 1e-4f), 0.9999f);
        float b0 = __logf(1.f - pred) * pred * pred;  // what phase 0 counted
        if (center) {               // heatmap == 1.0 exactly
          float om = 1.f - pred;
          posS += __logf(pred) * om * om;
          negS -= b0;
          np += 1;
        } else {                    // heatmap = h in (0,1)
          float om = 1.f - h;
          float w4 = om * om; w4 *= w4;
          negS += b0 * (w4 - 1.f);
        }
      }
    }
  }

  // ---- phase 3: wh / IoU loss for row k of image b (descending winner scan) ----
  float rwS = 0.f, wlS = 0.f;
  if (tid < 128) {
    int py = k, px = tid;
    int win = -1, dx = 0, dy = 0;
    for (int j = KK - 1; j >= 0; --j) {
      int pj = spk[j];
      int dxx = px - (pj & 255), dyy = py - ((pj >> 8) & 255);
      if (iabs_(dxx) <= ((pj >> 16) & 255) && iabs_(dyy) <= ((pj >> 24) & 255)) {
        win = j; dx = dxx; dy = dyy; break;
      }
    }
    if (win >= 0) {
      float g = __expf(-(float)(dy * dy) * si2y[win] - (float)(dx * dx) * si2x[win]);
      float rw = g * scf[win];
      float xs = (float)px * 4.f, ys = (float)py * 4.f;
      float tl = xs - sx1[win], tt = ys - sy1[win];
      float tr2 = sx2[win] - xs, tb2 = sy2[win] - ys;
      int lp = (k << 7) | tid;
      int base = b * 4 * NPIX + lp;
      float pl = wh[base] * 16.f;
      float pt = wh[base + NPIX] * 16.f;
      float pr = wh[base + 2 * NPIX] * 16.f;
      float pb = wh[base + 3 * NPIX] * 16.f;
      float ta = (tl + tr2) * (tt + tb2);
      float pa = (pl + pr) * (pt + pb);
      float wi = fminf(pl, tl) + fminf(pr, tr2);
      float hi = fminf(pt, tt) + fminf(pb, tb2);
      float ai = wi * hi;
      float au = ta + pa - ai;
      float iou = (ai + 1.f) / (au + 1.f);
      rwS = rw;
      wlS = (1.f - iou) * rw;
    }
  }

  // ---- phase 4: block reduce -> global atomics; last block finalizes ----
  for (int off = 32; off; off >>= 1) {
    negS += __shfl_down(negS, off);
    posS += __shfl_down(posS, off);
    np   += __shfl_down(np, off);
    rwS  += __shfl_down(rwS, off);
    wlS  += __shfl_down(wlS, off);
  }
  __shared__ float r0[4], r1[4], r2[4], r3[4];
  __shared__ int   r4[4];
  int wave = tid >> 6, lane = tid & 63;
  if (lane == 0) { r0[wave] = negS; r1[wave] = posS; r2[wave] = rwS; r3[wave] = wlS; r4[wave] = np; }
  __syncthreads();
  if (tid == 0) {
    double n_ = 0.0, p_ = 0.0, rw_ = 0.0, wl_ = 0.0; int np_ = 0;
    for (int i = 0; i < 4; ++i) {
      n_ += (double)r0[i]; p_ += (double)r1[i];
      rw_ += (double)r2[i]; wl_ += (double)r3[i]; np_ += r4[i];
    }
    atomicAdd(&acc->neg, n_);
    atomicAdd(&acc->pos, p_);
    atomicAdd(&acc->rw, rw_);
    atomicAdd(&acc->wl, wl_);
    atomicAdd(&acc->np, np_);
    __threadfence();                       // release: accs visible before counter bump
    int old = atomicAdd(&acc->counter, 1);
    if (old == NBLK - 1) {                 // last block finalizes
      __threadfence();                     // acquire
      double negT = atomicAdd(&acc->neg, 0.0);
      double posT = atomicAdd(&acc->pos, 0.0);
      double rwT  = atomicAdd(&acc->rw, 0.0);
      double wlT  = atomicAdd(&acc->wl, 0.0);
      int    npT  = atomicAdd(&acc->np, 0);
      double hm_loss = (npT > 0) ? -(posT + negT) / fmax((double)npT, 1.0) : -negT;
      double wh_loss = wlT / fmax(rwT, 1.0);
      out[0] = (float)(hm_loss + wh_loss);
    }
  }
}

extern "C" void kernel_launch(void* const* d_in, const int* in_sizes, int n_in,
                              void* d_out, int out_size, void* d_ws, size_t ws_size,
                              hipStream_t stream) {
  (void)in_sizes; (void)n_in; (void)out_size; (void)ws_size;
  const float* hm  = (const float*)d_in[0];
  const float* wh  = (const float*)d_in[1];
  const float* tgt = (const float*)d_in[2];
  const void*  msk = d_in[3];
  float* out = (float*)d_out;
  Accum* acc = (Accum*)d_ws;

  hipMemsetAsync(d_ws, 0, 64, stream);
  k_all<<<NBLK, 256, 0, stream>>>(hm, wh, tgt, msk, acc, out);
}

// Round 6
// 288.170 us; speedup vs baseline: 1.0112x; 1.0112x over previous
//
#include <hip/hip_runtime.h>
#include <math.h>

#define BB 16
#define KK 128
#define NC 80
#define OH 128
#define OW 128
#define NPIX (OH * OW)
#define NBLK (BB * KK)
#define ALPHA_C 0.54f

// ---------------- ws layout (bytes) ----------------
//   0:    Accum (counter, np, neg, pos, rw, wl) -- zeroed by k_prep block 0
//   64:   packed int[2048]   (cx | cy<<8 | wr<<16 | hr<<24; cx=255 => never covers)
//   8256: cls   int[2048]
//   16448: i2x  float[2048]
//   24640: i2y  float[2048]
//   32832: coef float[2048]
//   41024: x1   float[2048]
//   49216: y1   float[2048]
//   57408: x2   float[2048]
//   65600: y2   float[2048]
//   73792: winmap int[16*16384]  (1 MB)

struct Accum {
  int counter;
  int np;
  double neg;
  double pos;
  double rw;
  double wl;
};

__device__ __forceinline__ int iabs_(int x) { return x < 0 ? -x : x; }

// baseline negative-loss term at heatmap==0; MUST be identical in dense and corr paths
__device__ __forceinline__ float neg_base(float v) {
  float pred = 1.f / (1.f + __expf(-v));
  pred = fminf(fmaxf(pred, 1e-4f), 0.9999f);
  return __logf(1.f - pred) * pred * pred;
}

// ---------------- K1: per-image prep (sort + params + LDS winner-map scatter) --------
// VERBATIM round-3 structure (128 threads; all __syncthreads wave-uniform), plus
// acc zeroing by block 0.
__global__ __launch_bounds__(128) void k_prep(
    const float* __restrict__ tgt, const void* __restrict__ maskp,
    int* __restrict__ w_packed, int* __restrict__ w_cls,
    float* __restrict__ w_i2x, float* __restrict__ w_i2y,
    float* __restrict__ w_coef,
    float* __restrict__ w_x1, float* __restrict__ w_y1,
    float* __restrict__ w_x2, float* __restrict__ w_y2,
    int* __restrict__ winmap, Accum* __restrict__ acc)
{
  int b = blockIdx.x;
  int tid = threadIdx.x;
  __shared__ int   wm[NPIX];          // 64 KiB winner map for this image
  __shared__ float skey[KK];
  __shared__ int   sidx[KK];
  __shared__ float sal[KK];
  __shared__ int   anyBig, anyF1;

  // zero the global accumulator (k_main is stream-ordered after this kernel)
  if (b == 0 && tid < 12) ((int*)acc)[tid] = 0;

  if (tid == 0) { anyBig = 0; anyF1 = 0; }
  // clear LDS winner map
  for (int i = tid; i < NPIX; i += 128) wm[i] = -1;
  __syncthreads();
  // mask dtype auto-detect: scan first 512 words (2048 bytes, safe for all layouts)
  const unsigned int* mu = (const unsigned int*)maskp;
  for (int i = tid; i < 512; i += 128) {
    unsigned int u = mu[i];
    if (u == 0x3f800000u) anyF1 = 1;
    else if (u > 1u) anyBig = 1;
  }
  __syncthreads();
  int mode = anyF1 ? 2 : (anyBig ? 1 : 0);  // 0=int32, 1=uint8, 2=float32

  const float* tb = tgt + b * KK * 5;
  int gi = b * KK + tid;
  bool m;
  if (mode == 2)      m = ((const float*)maskp)[gi] != 0.f;
  else if (mode == 1) m = ((const unsigned char*)maskp)[gi] != 0;
  else                m = ((const int*)maskp)[gi] != 0;

  float x1 = tb[tid * 5 + 1], y1 = tb[tid * 5 + 2];
  float x2 = tb[tid * 5 + 3], y2 = tb[tid * 5 + 4];
  float alog = logf((x2 - x1) * (y2 - y1));
  // ascending sort of (valid ? -area_log : +inf) == argsort(-sort_key)
  skey[tid] = m ? -alog : INFINITY;
  sidx[tid] = tid;
  __syncthreads();

  for (int size = 2; size <= KK; size <<= 1) {
    for (int stride = size >> 1; stride > 0; stride >>= 1) {
      int i = tid, j = i ^ stride;
      if (j > i) {
        bool up = ((i & size) == 0);
        float ki = skey[i], kj = skey[j];
        if (up ? (ki > kj) : (ki < kj)) {
          skey[i] = kj; skey[j] = ki;
          int t = sidx[i]; sidx[i] = sidx[j]; sidx[j] = t;
        }
      }
      __syncthreads();
    }
  }

  int o = sidx[tid];
  bool vo;
  int go = b * KK + o;
  if (mode == 2)      vo = ((const float*)maskp)[go] != 0.f;
  else if (mode == 1) vo = ((const unsigned char*)maskp)[go] != 0;
  else                vo = ((const int*)maskp)[go] != 0;

  float bx1 = tb[o * 5 + 1], by1 = tb[o * 5 + 2];
  float bx2 = tb[o * 5 + 3], by2 = tb[o * 5 + 4];
  int   cls = (int)tb[o * 5 + 0];
  float al = vo ? logf((bx2 - bx1) * (by2 - by1)) : 0.f;
  sal[tid] = al;
  __syncthreads();
  float al0 = sal[0];
  float factor = 2.f - al / (al0 + 1e-7f);

  float fx1 = fminf(fmaxf(bx1 * 0.25f, 0.f), (float)(OW - 1));
  float fy1 = fminf(fmaxf(by1 * 0.25f, 0.f), (float)(OH - 1));
  float fx2 = fminf(fmaxf(bx2 * 0.25f, 0.f), (float)(OW - 1));
  float fy2 = fminf(fmaxf(by2 * 0.25f, 0.f), (float)(OH - 1));
  float fh = fy2 - fy1, fw = fx2 - fx1;
  int cx = (int)((bx1 + bx2) * 0.125f);
  int cy = (int)((by1 + by2) * 0.125f);
  int hr = (int)(fh * 0.5f * ALPHA_C);
  int wr = (int)(fw * 0.5f * ALPHA_C);
  float sy = (float)(2 * hr + 1) / 6.f;
  float sx = (float)(2 * wr + 1) / 6.f;
  float i2y = 1.f / (2.f * sy * sy);
  float i2x = 1.f / (2.f * sx * sx);
  bool inb = (cx >= 0 && cx < OW && cy >= 0 && cy < OH);
  bool cov = vo && inb;

  // div = sum of G over the map (separable: (sum gy)*(sum gx))
  float sgy = 0.f, sgx = 0.f;
  if (cov) {
    int y0 = max(0, cy - hr), y1i = min(OH - 1, cy + hr);
    for (int y = y0; y <= y1i; ++y) { float d = (float)(y - cy); sgy += __expf(-d * d * i2y); }
    int x0 = max(0, cx - wr), x1i = min(OW - 1, cx + wr);
    for (int x = x0; x <= x1i; ++x) { float d = (float)(x - cx); sgx += __expf(-d * d * i2x); }
  }
  float div = cov ? sgy * sgx : 0.f;
  float coef = factor / (div + 1e-7f);

  int pk;
  if (cov) pk = (cx & 255) | ((cy & 255) << 8) | ((wr & 255) << 16) | ((hr & 255) << 24);
  else     pk = 0x000000FF;  // cx=255: |px-255| <= wr impossible for px in [0,128)

  int idx = b * KK + tid;
  w_packed[idx] = pk;  w_cls[idx] = cls;
  w_i2x[idx] = i2x;    w_i2y[idx] = i2y;  w_coef[idx] = coef;
  w_x1[idx] = bx1;     w_y1[idx] = by1;   w_x2[idx] = bx2;  w_y2[idx] = by2;

  // winner-map scatter into LDS: winner = max covering sorted index (fire-and-forget)
  if (cov) {
    int py0 = max(0, cy - hr), py1 = min(OH - 1, cy + hr);
    int px0 = max(0, cx - wr), px1 = min(OW - 1, cx + wr);
    for (int py = py0; py <= py1; ++py) {
      int rb = py * OW;
      for (int px = px0; px <= px1; ++px) atomicMax(&wm[rb + px], tid);
    }
  }
  __syncthreads();
  // coalesced write-out, 16 B per lane
  int4* gout = (int4*)(winmap + b * NPIX);
  const int4* lin = (const int4*)wm;
  for (int i = tid; i < NPIX / 4; i += 128) gout[i] = lin[i];
}

// ---------------- K2: fused dense baseline + sparse corrections + wh/IoU + finalize --
__global__ __launch_bounds__(256) void k_main(
    const float* hm, const float* __restrict__ wh, const int* __restrict__ winmap,
    const int* __restrict__ w_packed, const int* __restrict__ w_cls,
    const float* __restrict__ w_i2x, const float* __restrict__ w_i2y,
    const float* __restrict__ w_coef,
    const float* __restrict__ w_x1, const float* __restrict__ w_y1,
    const float* __restrict__ w_x2, const float* __restrict__ w_y2,
    Accum* __restrict__ acc, float* __restrict__ out)
{
  int tid = threadIdx.x;
  int blk = blockIdx.x;
  int b = blk >> 7;          // image
  int k = blk & (KK - 1);    // sorted box index handled by this block

  __shared__ int   spk[KK], scl[KK], sl[KK];
  __shared__ float si2x[KK], si2y[KK], scf[KK];
  __shared__ float sx1[KK], sy1[KK], sx2[KK], sy2[KK];
  __shared__ int   snS;

  if (tid < KK) {
    int g = b * KK + tid;
    spk[tid] = w_packed[g]; scl[tid] = w_cls[g];
    si2x[tid] = w_i2x[g];   si2y[tid] = w_i2y[g];  scf[tid] = w_coef[g];
    sx1[tid] = w_x1[g];     sy1[tid] = w_y1[g];
    sx2[tid] = w_x2[g];     sy2[tid] = w_y2[g];
  }

  // ---- dense heatmap==0 baseline (independent of LDS; overlaps staging) ----
  float negS = 0.f;
  {
    const float4* hm4 = (const float4*)hm;
    const int n4 = BB * NC * NPIX / 4;
    int stride = gridDim.x * blockDim.x;
    for (int i = blk * 256 + tid; i < n4; i += stride) {
      float4 v = hm4[i];
      negS += neg_base(v.x) + neg_base(v.y) + neg_base(v.z) + neg_base(v.w);
    }
  }
  __syncthreads();

  int pk = spk[k];
  int cx = pk & 255, cy = (pk >> 8) & 255, wr = (pk >> 16) & 255, hr = (pk >> 24) & 255;
  int c = scl[k];

  // ---- wave 0: ballot-compact same-class box indices (ascending) ----
  if (cx != 255 && tid < 64) {
    unsigned long long below = (1ull << tid) - 1ull;
    bool p0 = (scl[tid] == c);
    unsigned long long m0 = __ballot(p0);
    int n0 = __popcll(m0);
    if (p0) sl[__popcll(m0 & below)] = tid;
    bool p1 = (scl[tid + 64] == c);
    unsigned long long m1 = __ballot(p1);
    if (p1) sl[n0 + __popcll(m1 & below)] = tid + 64;
    if (tid == 0) snS = n0 + __popcll(m1);
  }
  __syncthreads();

  // ---- sparse heatmap correction for box k: 16x16 thread tile over the window ----
  float posS = 0.f;
  int np = 0;
  if (cx != 255) {
    int nS = snS;
    int W = 2 * wr + 1, H = 2 * hr + 1;
    int tr = tid >> 4, tc = tid & 15;
    for (int r0 = 0; r0 < H; r0 += 16) {
      int row = r0 + tr;
      int py = cy - hr + row;
      if (row >= H || py < 0 || py >= OH) continue;
      for (int c0 = 0; c0 < W; c0 += 16) {
        int col = c0 + tc;
        int px = cx - wr + col;
        if (col >= W || px < 0 || px >= OW) continue;
        float h = 0.f;
        bool center = false, resp = true;
        for (int u = 0; u < nS; ++u) {
          int j = sl[u];
          int pj = spk[j];
          int dx = px - (pj & 255), dy = py - ((pj >> 8) & 255);
          if (iabs_(dx) <= ((pj >> 16) & 255) && iabs_(dy) <= ((pj >> 24) & 255)) {
            if (j < k) { resp = false; break; }  // smaller sorted index owns this cell
            float g = __expf(-(float)(dy * dy) * si2y[j] - (float)(dx * dx) * si2x[j]);
            h = fmaxf(h, g);
            center |= (dx == 0 && dy == 0);
          }
        }
        if (!resp) continue;
        float v = hm[((b * NC + c) * OH + py) * OW + px];
        float pred = 1.f / (1.f + __expf(-v));
        pred = fminf(fmaxf(pred, 1e-4f), 0.9999f);
        float b0 = __logf(1.f - pred) * pred * pred;  // what the dense pass counted
        if (center) {               // heatmap == 1.0 exactly
          float om = 1.f - pred;
          posS += __logf(pred) * om * om;
          negS -= b0;
          np += 1;
        } else {                    // heatmap = h in (0,1)
          float om = 1.f - h;
          float w4 = om * om; w4 *= w4;
          negS += b0 * (w4 - 1.f);
        }
      }
    }
  }

  // ---- wh / IoU loss: this block handles 128 pixels of image b (row k) ----
  float rwS = 0.f, wlS = 0.f;
  if (tid < 128) {
    int lp = (k << 7) | tid;         // local pixel: py = k, px = tid
    int py = k, px = tid;
    int win = winmap[b * NPIX + lp];
    if (win >= 0) {
      int pj = spk[win];
      int dx = px - (pj & 255), dy = py - ((pj >> 8) & 255);
      float g = __expf(-(float)(dy * dy) * si2y[win] - (float)(dx * dx) * si2x[win]);
      float rw = g * scf[win];
      float xs = (float)px * 4.f, ys = (float)py * 4.f;
      float tl = xs - sx1[win], tt = ys - sy1[win];
      float tr2 = sx2[win] - xs, tb2 = sy2[win] - ys;
      int base = b * 4 * NPIX + lp;
      float pl = wh[base] * 16.f;
      float pt = wh[base + NPIX] * 16.f;
      float pr = wh[base + 2 * NPIX] * 16.f;
      float pb = wh[base + 3 * NPIX] * 16.f;
      float ta = (tl + tr2) * (tt + tb2);
      float pa = (pl + pr) * (pt + pb);
      float wi = fminf(pl, tl) + fminf(pr, tr2);
      float hi = fminf(pt, tt) + fminf(pb, tb2);
      float ai = wi * hi;
      float au = ta + pa - ai;
      float iou = (ai + 1.f) / (au + 1.f);
      rwS = rw;
      wlS = (1.f - iou) * rw;
    }
  }

  // ---- block reduce -> global atomics; last block finalizes ----
  for (int off = 32; off; off >>= 1) {
    negS += __shfl_down(negS, off);
    posS += __shfl_down(posS, off);
    np   += __shfl_down(np, off);
    rwS  += __shfl_down(rwS, off);
    wlS  += __shfl_down(wlS, off);
  }
  __shared__ float r0[4], r1[4], r2[4], r3[4];
  __shared__ int   r4[4];
  int wave = tid >> 6, lane = tid & 63;
  if (lane == 0) { r0[wave] = negS; r1[wave] = posS; r2[wave] = rwS; r3[wave] = wlS; r4[wave] = np; }
  __syncthreads();
  if (tid == 0) {
    double n_ = 0.0, p_ = 0.0, rw_ = 0.0, wl_ = 0.0; int np_ = 0;
    for (int i = 0; i < 4; ++i) {
      n_ += (double)r0[i]; p_ += (double)r1[i];
      rw_ += (double)r2[i]; wl_ += (double)r3[i]; np_ += r4[i];
    }
    atomicAdd(&acc->neg, n_);
    atomicAdd(&acc->pos, p_);
    atomicAdd(&acc->rw, rw_);
    atomicAdd(&acc->wl, wl_);
    atomicAdd(&acc->np, np_);
    __threadfence();                       // release: accs visible before counter bump
    int old = atomicAdd(&acc->counter, 1);
    if (old == NBLK - 1) {                 // last block finalizes
      __threadfence();                     // acquire
      double negT = atomicAdd(&acc->neg, 0.0);
      double posT = atomicAdd(&acc->pos, 0.0);
      double rwT  = atomicAdd(&acc->rw, 0.0);
      double wlT  = atomicAdd(&acc->wl, 0.0);
      int    npT  = atomicAdd(&acc->np, 0);
      double hm_loss = (npT > 0) ? -(posT + negT) / fmax((double)npT, 1.0) : -negT;
      double wh_loss = wlT / fmax(rwT, 1.0);
      out[0] = (float)(hm_loss + wh_loss);
    }
  }
}

extern "C" void kernel_launch(void* const* d_in, const int* in_sizes, int n_in,
                              void* d_out, int out_size, void* d_ws, size_t ws_size,
                              hipStream_t stream) {
  (void)in_sizes; (void)n_in; (void)out_size; (void)ws_size;
  const float* hm  = (const float*)d_in[0];
  const float* wh  = (const float*)d_in[1];
  const float* tgt = (const float*)d_in[2];
  const void*  msk = d_in[3];
  float* out = (float*)d_out;
  char* ws = (char*)d_ws;

  Accum*  acc      = (Accum*)(ws + 0);
  int*    w_packed = (int*)(ws + 64);
  int*    w_cls    = (int*)(ws + 8256);
  float*  w_i2x    = (float*)(ws + 16448);
  float*  w_i2y    = (float*)(ws + 24640);
  float*  w_coef   = (float*)(ws + 32832);
  float*  w_x1     = (float*)(ws + 41024);
  float*  w_y1     = (float*)(ws + 49216);
  float*  w_x2     = (float*)(ws + 57408);
  float*  w_y2     = (float*)(ws + 65600);
  int*    winmap   = (int*)(ws + 73792);

  k_prep<<<BB, 128, 0, stream>>>(tgt, msk, w_packed, w_cls, w_i2x, w_i2y, w_coef,
                                 w_x1, w_y1, w_x2, w_y2, winmap, acc);
  k_main<<<NBLK, 256, 0, stream>>>(hm, wh, winmap,
                                   w_packed, w_cls, w_i2x, w_i2y, w_coef,
                                   w_x1, w_y1, w_x2, w_y2, acc, out);
}

// Round 7
// 156.150 us; speedup vs baseline: 1.8661x; 1.8455x over previous
//
#include <hip/hip_runtime.h>
#include <math.h>

#define BB 16
#define KK 128
#define NC 80
#define OH 128
#define OW 128
#define NPIX (OH * OW)
#define ALPHA_C 0.54f

// ---------------- ws layout (bytes) ----------------
//   packed int[2048]   @ 0        (cx | cy<<8 | wr<<16 | hr<<24; cx=255 => never covers)
//   cls    int[2048]   @ 8192
//   i2x    float[2048] @ 16384    (1/(2*sx^2))
//   i2y    float[2048] @ 24576
//   coef   float[2048] @ 32768    (factor / (div + 1e-7))
//   x1     float[2048] @ 40960
//   y1     float[2048] @ 49152
//   x2     float[2048] @ 57344
//   y2     float[2048] @ 65536
//   p_neg  double[2048] @ 73728
//   p_pos  double[2048] @ 90112
//   p_np   int   [2048] @ 106496
//   p_rw   double[2048] @ 114688
//   p_wl   double[2048] @ 131072
//   winmap int[16*16384] @ 147456  (1 MB)
// total 1196032 bytes
//
// NOTE (r6 post-mortem): do NOT replace the partial-array + k_final tail with
// per-block f64 atomics + __threadfence + last-block finalize. On gfx950 the
// device-scope fence per block (2048×) forces L2 writeback/invalidate (XCD
// non-coherence) and the same-cacheline f64 RMWs serialize — measured +120 µs
// on k_main (r4: 195 µs, r6: 175 µs vs this structure's ≤51 µs).

__device__ __forceinline__ int iabs_(int x) { return x < 0 ? -x : x; }

// baseline negative-loss term at heatmap==0; MUST be identical in dense and corr paths
__device__ __forceinline__ float neg_base(float v) {
  float pred = 1.f / (1.f + __expf(-v));
  pred = fminf(fmaxf(pred, 1e-4f), 0.9999f);
  return __logf(1.f - pred) * pred * pred;
}

// ---------------- K1: per-image prep (sort + params + LDS winner-map scatter) --------
__global__ __launch_bounds__(128) void k_prep(
    const float* __restrict__ tgt, const void* __restrict__ maskp,
    int* __restrict__ w_packed, int* __restrict__ w_cls,
    float* __restrict__ w_i2x, float* __restrict__ w_i2y,
    float* __restrict__ w_coef,
    float* __restrict__ w_x1, float* __restrict__ w_y1,
    float* __restrict__ w_x2, float* __restrict__ w_y2,
    int* __restrict__ winmap)
{
  int b = blockIdx.x;
  int tid = threadIdx.x;
  __shared__ int   wm[NPIX];          // 64 KiB winner map for this image
  __shared__ float skey[KK];
  __shared__ int   sidx[KK];
  __shared__ float sal[KK];
  __shared__ int   anyBig, anyF1;

  if (tid == 0) { anyBig = 0; anyF1 = 0; }
  // clear LDS winner map
  for (int i = tid; i < NPIX; i += 128) wm[i] = -1;
  __syncthreads();
  // mask dtype auto-detect: scan first 512 words (2048 bytes, safe for all layouts)
  const unsigned int* mu = (const unsigned int*)maskp;
  for (int i = tid; i < 512; i += 128) {
    unsigned int u = mu[i];
    if (u == 0x3f800000u) anyF1 = 1;
    else if (u > 1u) anyBig = 1;
  }
  __syncthreads();
  int mode = anyF1 ? 2 : (anyBig ? 1 : 0);  // 0=int32, 1=uint8, 2=float32

  const float* tb = tgt + b * KK * 5;
  int gi = b * KK + tid;
  bool m;
  if (mode == 2)      m = ((const float*)maskp)[gi] != 0.f;
  else if (mode == 1) m = ((const unsigned char*)maskp)[gi] != 0;
  else                m = ((const int*)maskp)[gi] != 0;

  float x1 = tb[tid * 5 + 1], y1 = tb[tid * 5 + 2];
  float x2 = tb[tid * 5 + 3], y2 = tb[tid * 5 + 4];
  float alog = logf((x2 - x1) * (y2 - y1));
  // ascending sort of (valid ? -area_log : +inf) == argsort(-sort_key)
  skey[tid] = m ? -alog : INFINITY;
  sidx[tid] = tid;
  __syncthreads();

  for (int size = 2; size <= KK; size <<= 1) {
    for (int stride = size >> 1; stride > 0; stride >>= 1) {
      int i = tid, j = i ^ stride;
      if (j > i) {
        bool up = ((i & size) == 0);
        float ki = skey[i], kj = skey[j];
        if (up ? (ki > kj) : (ki < kj)) {
          skey[i] = kj; skey[j] = ki;
          int t = sidx[i]; sidx[i] = sidx[j]; sidx[j] = t;
        }
      }
      __syncthreads();
    }
  }

  int o = sidx[tid];
  bool vo;
  int go = b * KK + o;
  if (mode == 2)      vo = ((const float*)maskp)[go] != 0.f;
  else if (mode == 1) vo = ((const unsigned char*)maskp)[go] != 0;
  else                vo = ((const int*)maskp)[go] != 0;

  float bx1 = tb[o * 5 + 1], by1 = tb[o * 5 + 2];
  float bx2 = tb[o * 5 + 3], by2 = tb[o * 5 + 4];
  int   cls = (int)tb[o * 5 + 0];
  float al = vo ? logf((bx2 - bx1) * (by2 - by1)) : 0.f;
  sal[tid] = al;
  __syncthreads();
  float al0 = sal[0];
  float factor = 2.f - al / (al0 + 1e-7f);

  float fx1 = fminf(fmaxf(bx1 * 0.25f, 0.f), (float)(OW - 1));
  float fy1 = fminf(fmaxf(by1 * 0.25f, 0.f), (float)(OH - 1));
  float fx2 = fminf(fmaxf(bx2 * 0.25f, 0.f), (float)(OW - 1));
  float fy2 = fminf(fmaxf(by2 * 0.25f, 0.f), (float)(OH - 1));
  float fh = fy2 - fy1, fw = fx2 - fx1;
  int cx = (int)((bx1 + bx2) * 0.125f);
  int cy = (int)((by1 + by2) * 0.125f);
  int hr = (int)(fh * 0.5f * ALPHA_C);
  int wr = (int)(fw * 0.5f * ALPHA_C);
  float sy = (float)(2 * hr + 1) / 6.f;
  float sx = (float)(2 * wr + 1) / 6.f;
  float i2y = 1.f / (2.f * sy * sy);
  float i2x = 1.f / (2.f * sx * sx);
  bool inb = (cx >= 0 && cx < OW && cy >= 0 && cy < OH);
  bool cov = vo && inb;

  // div = sum of G over the map (separable: (sum gy)*(sum gx))
  float sgy = 0.f, sgx = 0.f;
  if (cov) {
    int y0 = max(0, cy - hr), y1i = min(OH - 1, cy + hr);
    for (int y = y0; y <= y1i; ++y) { float d = (float)(y - cy); sgy += __expf(-d * d * i2y); }
    int x0 = max(0, cx - wr), x1i = min(OW - 1, cx + wr);
    for (int x = x0; x <= x1i; ++x) { float d = (float)(x - cx); sgx += __expf(-d * d * i2x); }
  }
  float div = cov ? sgy * sgx : 0.f;
  float coef = factor / (div + 1e-7f);

  int pk;
  if (cov) pk = (cx & 255) | ((cy & 255) << 8) | ((wr & 255) << 16) | ((hr & 255) << 24);
  else     pk = 0x000000FF;  // cx=255: |px-255| <= wr impossible for px in [0,128), wr<=127

  int idx = b * KK + tid;
  w_packed[idx] = pk;  w_cls[idx] = cls;
  w_i2x[idx] = i2x;    w_i2y[idx] = i2y;  w_coef[idx] = coef;
  w_x1[idx] = bx1;     w_y1[idx] = by1;   w_x2[idx] = bx2;  w_y2[idx] = by2;

  // winner-map scatter into LDS: winner = max covering sorted index (fire-and-forget)
  if (cov) {
    int py0 = max(0, cy - hr), py1 = min(OH - 1, cy + hr);
    int px0 = max(0, cx - wr), px1 = min(OW - 1, cx + wr);
    for (int py = py0; py <= py1; ++py) {
      int rb = py * OW;
      for (int px = px0; px <= px1; ++px) atomicMax(&wm[rb + px], tid);
    }
  }
  __syncthreads();
  // coalesced write-out, 16 B per lane
  int4* gout = (int4*)(winmap + b * NPIX);
  const int4* lin = (const int4*)wm;
  for (int i = tid; i < NPIX / 4; i += 128) gout[i] = lin[i];
}

// ---------------- K2: fused dense baseline + sparse corrections + wh/IoU ----------------
__global__ __launch_bounds__(256) void k_main(
    const float* hm, const float* __restrict__ wh, const int* __restrict__ winmap,
    const int* __restrict__ w_packed, const int* __restrict__ w_cls,
    const float* __restrict__ w_i2x, const float* __restrict__ w_i2y,
    const float* __restrict__ w_coef,
    const float* __restrict__ w_x1, const float* __restrict__ w_y1,
    const float* __restrict__ w_x2, const float* __restrict__ w_y2,
    double* __restrict__ p_neg, double* __restrict__ p_pos, int* __restrict__ p_np,
    double* __restrict__ p_rw, double* __restrict__ p_wl)
{
  int tid = threadIdx.x;
  int blk = blockIdx.x;
  int b = blk >> 7;          // image
  int k = blk & (KK - 1);    // sorted box index handled by this block

  __shared__ int   spk[KK], scl[KK], sl[KK];
  __shared__ float si2x[KK], si2y[KK], scf[KK];
  __shared__ float sx1[KK], sy1[KK], sx2[KK], sy2[KK];
  __shared__ int   snS;

  if (tid < KK) {
    int g = b * KK + tid;
    spk[tid] = w_packed[g]; scl[tid] = w_cls[g];
    si2x[tid] = w_i2x[g];   si2y[tid] = w_i2y[g];  scf[tid] = w_coef[g];
    sx1[tid] = w_x1[g];     sy1[tid] = w_y1[g];
    sx2[tid] = w_x2[g];     sy2[tid] = w_y2[g];
  }

  // ---- dense heatmap==0 baseline (independent of LDS; overlaps staging) ----
  float negS = 0.f;
  {
    const float4* hm4 = (const float4*)hm;
    const int n4 = BB * NC * NPIX / 4;
    int stride = gridDim.x * blockDim.x;
    for (int i = blk * 256 + tid; i < n4; i += stride) {
      float4 v = hm4[i];
      negS += neg_base(v.x) + neg_base(v.y) + neg_base(v.z) + neg_base(v.w);
    }
  }
  __syncthreads();

  int pk = spk[k];
  int cx = pk & 255, cy = (pk >> 8) & 255, wr = (pk >> 16) & 255, hr = (pk >> 24) & 255;
  int c = scl[k];

  // ---- wave 0: ballot-compact same-class box indices (ascending) ----
  if (cx != 255 && tid < 64) {
    unsigned long long below = (1ull << tid) - 1ull;
    bool p0 = (scl[tid] == c);
    unsigned long long m0 = __ballot(p0);
    int n0 = __popcll(m0);
    if (p0) sl[__popcll(m0 & below)] = tid;
    bool p1 = (scl[tid + 64] == c);
    unsigned long long m1 = __ballot(p1);
    if (p1) sl[n0 + __popcll(m1 & below)] = tid + 64;
    if (tid == 0) snS = n0 + __popcll(m1);
  }
  __syncthreads();

  // ---- sparse heatmap correction for box k: 16x16 thread tile over the window ----
  float posS = 0.f;
  int np = 0;
  if (cx != 255) {
    int nS = snS;
    int W = 2 * wr + 1, H = 2 * hr + 1;
    int tr = tid >> 4, tc = tid & 15;
    for (int r0 = 0; r0 < H; r0 += 16) {
      int row = r0 + tr;
      int py = cy - hr + row;
      if (row >= H || py < 0 || py >= OH) continue;
      for (int c0 = 0; c0 < W; c0 += 16) {
        int col = c0 + tc;
        int px = cx - wr + col;
        if (col >= W || px < 0 || px >= OW) continue;
        float h = 0.f;
        bool center = false, resp = true;
        for (int u = 0; u < nS; ++u) {
          int j = sl[u];
          int pj = spk[j];
          int dx = px - (pj & 255), dy = py - ((pj >> 8) & 255);
          if (iabs_(dx) <= ((pj >> 16) & 255) && iabs_(dy) <= ((pj >> 24) & 255)) {
            if (j < k) { resp = false; break; }  // smaller sorted index owns this cell
            float g = __expf(-(float)(dy * dy) * si2y[j] - (float)(dx * dx) * si2x[j]);
            h = fmaxf(h, g);
            center |= (dx == 0 && dy == 0);
          }
        }
        if (!resp) continue;
        float v = hm[((b * NC + c) * OH + py) * OW + px];
        float pred = 1.f / (1.f + __expf(-v));
        pred = fminf(fmaxf(pred, 1e-4f), 0.9999f);
        float b0 = __logf(1.f - pred) * pred * pred;  // what the dense pass counted
        if (center) {               // heatmap == 1.0 exactly
          float om = 1.f - pred;
          posS += __logf(pred) * om * om;
          negS -= b0;
          np += 1;
        } else {                    // heatmap = h in (0,1)
          float om = 1.f - h;
          float w4 = om * om; w4 *= w4;
          negS += b0 * (w4 - 1.f);
        }
      }
    }
  }

  // ---- wh / IoU loss: this block handles 128 pixels of image b (row k) ----
  float rwS = 0.f, wlS = 0.f;
  if (tid < 128) {
    int lp = (k << 7) | tid;         // local pixel: py = k, px = tid
    int py = k, px = tid;
    int win = winmap[b * NPIX + lp];
    if (win >= 0) {
      int pj = spk[win];
      int dx = px - (pj & 255), dy = py - ((pj >> 8) & 255);
      float g = __expf(-(float)(dy * dy) * si2y[win] - (float)(dx * dx) * si2x[win]);
      float rw = g * scf[win];
      float xs = (float)px * 4.f, ys = (float)py * 4.f;
      float tl = xs - sx1[win], tt = ys - sy1[win];
      float tr2 = sx2[win] - xs, tb2 = sy2[win] - ys;
      int base = b * 4 * NPIX + lp;
      float pl = wh[base] * 16.f;
      float pt = wh[base + NPIX] * 16.f;
      float pr = wh[base + 2 * NPIX] * 16.f;
      float pb = wh[base + 3 * NPIX] * 16.f;
      float ta = (tl + tr2) * (tt + tb2);
      float pa = (pl + pr) * (pt + pb);
      float wi = fminf(pl, tl) + fminf(pr, tr2);
      float hi = fminf(pt, tt) + fminf(pb, tb2);
      float ai = wi * hi;
      float au = ta + pa - ai;
      float iou = (ai + 1.f) / (au + 1.f);
      rwS = rw;
      wlS = (1.f - iou) * rw;
    }
  }

  // ---- block reduction of 5 accumulators ----
  for (int off = 32; off; off >>= 1) {
    negS += __shfl_down(negS, off);
    posS += __shfl_down(posS, off);
    np   += __shfl_down(np, off);
    rwS  += __shfl_down(rwS, off);
    wlS  += __shfl_down(wlS, off);
  }
  __shared__ float r0[4], r1[4], r2[4], r3[4];
  __shared__ int   r4[4];
  int wave = tid >> 6, lane = tid & 63;
  if (lane == 0) { r0[wave] = negS; r1[wave] = posS; r2[wave] = rwS; r3[wave] = wlS; r4[wave] = np; }
  __syncthreads();
  if (tid == 0) {
    double n_ = 0.0, p_ = 0.0, rw_ = 0.0, wl_ = 0.0; int np_ = 0;
    for (int i = 0; i < 4; ++i) {
      n_ += (double)r0[i]; p_ += (double)r1[i];
      rw_ += (double)r2[i]; wl_ += (double)r3[i]; np_ += r4[i];
    }
    p_neg[blk] = n_;  p_pos[blk] = p_;  p_np[blk] = np_;
    p_rw[blk] = rw_;  p_wl[blk] = wl_;
  }
}

// ---------------- K3: final reduce ----------------
__global__ __launch_bounds__(256) void k_final(
    const double* __restrict__ p_neg, const double* __restrict__ p_pos,
    const int* __restrict__ p_np,
    const double* __restrict__ p_rw, const double* __restrict__ p_wl,
    float* __restrict__ out)
{
  int tid = threadIdx.x;
  double neg = 0.0, pos = 0.0, rw = 0.0, wl = 0.0;
  int np = 0;
  for (int i = tid; i < BB * KK; i += 256) {
    neg += p_neg[i];
    pos += p_pos[i];
    np  += p_np[i];
    rw  += p_rw[i];
    wl  += p_wl[i];
  }
  for (int off = 32; off; off >>= 1) {
    neg += __shfl_down(neg, off);
    pos += __shfl_down(pos, off);
    rw  += __shfl_down(rw, off);
    wl  += __shfl_down(wl, off);
    np  += __shfl_down(np, off);
  }
  __shared__ double s0[4], s1[4], s2[4], s3[4];
  __shared__ int s4[4];
  int wave = tid >> 6, lane = tid & 63;
  if (lane == 0) { s0[wave] = neg; s1[wave] = pos; s2[wave] = rw; s3[wave] = wl; s4[wave] = np; }
  __syncthreads();
  if (tid == 0) {
    double negT = 0, posT = 0, rwT = 0, wlT = 0; int npT = 0;
    for (int i = 0; i < 4; ++i) { negT += s0[i]; posT += s1[i]; rwT += s2[i]; wlT += s3[i]; npT += s4[i]; }
    double hm_loss = (npT > 0) ? -(posT + negT) / fmax((double)npT, 1.0) : -negT;
    double wh_loss = wlT / fmax(rwT, 1.0);
    out[0] = (float)(hm_loss + wh_loss);
  }
}

extern "C" void kernel_launch(void* const* d_in, const int* in_sizes, int n_in,
                              void* d_out, int out_size, void* d_ws, size_t ws_size,
                              hipStream_t stream) {
  (void)in_sizes; (void)n_in; (void)out_size; (void)ws_size;
  const float* hm  = (const float*)d_in[0];
  const float* wh  = (const float*)d_in[1];
  const float* tgt = (const float*)d_in[2];
  const void*  msk = d_in[3];
  float* out = (float*)d_out;
  char* ws = (char*)d_ws;

  int*    w_packed = (int*)(ws + 0);
  int*    w_cls    = (int*)(ws + 8192);
  float*  w_i2x    = (float*)(ws + 16384);
  float*  w_i2y    = (float*)(ws + 24576);
  float*  w_coef   = (float*)(ws + 32768);
  float*  w_x1     = (float*)(ws + 40960);
  float*  w_y1     = (float*)(ws + 49152);
  float*  w_x2     = (float*)(ws + 57344);
  float*  w_y2     = (float*)(ws + 65536);
  double* p_neg    = (double*)(ws + 73728);
  double* p_pos    = (double*)(ws + 90112);
  int*    p_np     = (int*)(ws + 106496);
  double* p_rw     = (double*)(ws + 114688);
  double* p_wl     = (double*)(ws + 131072);
  int*    winmap   = (int*)(ws + 147456);

  k_prep<<<BB, 128, 0, stream>>>(tgt, msk, w_packed, w_cls, w_i2x, w_i2y, w_coef,
                                 w_x1, w_y1, w_x2, w_y2, winmap);
  k_main<<<BB * KK, 256, 0, stream>>>(hm, wh, winmap,
                                      w_packed, w_cls, w_i2x, w_i2y, w_coef,
                                      w_x1, w_y1, w_x2, w_y2,
                                      p_neg, p_pos, p_np, p_rw, p_wl);
  k_final<<<1, 256, 0, stream>>>(p_neg, p_pos, p_np, p_rw, p_wl, out);
}